// Round 4
// baseline (286.816 us; speedup 1.0000x reference)
//
#include <hip/hip_runtime.h>
#include <math.h>

typedef __attribute__((ext_vector_type(8))) short bf16x8;
typedef __attribute__((ext_vector_type(8))) unsigned short u16x8;
typedef __attribute__((ext_vector_type(4))) float f32x4;

#define FEAT 128
#define KS   768
#define KT   1024
#define BM   32
#define KB   64
#define NTS  (KS / KB)   // 12
#define NTT  (KT / KB)   // 16

__device__ __forceinline__ unsigned short f2bf(float f) {
    unsigned u = __float_as_uint(f);
    u += 0x7fff + ((u >> 16) & 1);   // RNE; inputs well-scaled, no NaN/Inf
    return (unsigned short)(u >> 16);
}
__device__ __forceinline__ float bf2f(unsigned short h) {
    return __uint_as_float((unsigned)h << 16);
}

// Split W_s, W_t into bf16 hi/lo (same flat [FEAT][K] layout as source).
__global__ __launch_bounds__(256) void convert_w(
    const float* __restrict__ Ws, const float* __restrict__ Wt,
    unsigned short* __restrict__ WhiS, unsigned short* __restrict__ WloS,
    unsigned short* __restrict__ WhiT, unsigned short* __restrict__ WloT)
{
    const int NS = FEAT * KS;
    int e = blockIdx.x * 256 + threadIdx.x;
    if (e < NS) {
        float w = Ws[e];
        unsigned short h = f2bf(w);
        WhiS[e] = h;
        WloS[e] = f2bf(w - bf2f(h));
    } else {
        int e2 = e - NS;
        float w = Wt[e2];
        unsigned short h = f2bf(w);
        WhiT[e2] = h;
        WloT[e2] = f2bf(w - bf2f(h));
    }
}

// BM=32 rows/block, BOTH embeddings, bf16x3 MFMA, fused norm/dot epilogue.
// 256 threads = 4 waves (1M x 4N); per wave 32x32 out = 2x2 16x16 frags.
// grid 512 -> 2 independent blocks/CU (LDS ~41.5KB). Register double-buffer:
// prefetch tile t+1 before MFMA(t). LDS 16B-chunk XOR swizzle -> conflict-free.
__global__ __launch_bounds__(256, 2) void gemm_fused(
    const float* __restrict__ f_s, const float* __restrict__ f_t,
    const unsigned short* __restrict__ WhiS, const unsigned short* __restrict__ WloS,
    const unsigned short* __restrict__ WhiT, const unsigned short* __restrict__ WloT,
    const float* __restrict__ b_s, const float* __restrict__ b_t,
    float* __restrict__ partials)
{
    __shared__ unsigned short sAhi[BM][KB],   sAlo[BM][KB];    // 4KB each
    __shared__ unsigned short sBhi[FEAT][KB], sBlo[FEAT][KB];  // 16KB each
    __shared__ float sRed[BM][4][3];

    const int tid  = threadIdx.x;
    const int lane = tid & 63;
    const int wn   = tid >> 6;        // 0..3 (N split of FEAT)
    const int l15  = lane & 15;
    const int l4   = lane >> 4;
    const int row0 = blockIdx.x * BM;

    const int arow   = tid >> 3;      // 0..31 (A staging row)
    const int ak8    = tid & 7;       // 8-elem k-seg
    const int achunk = ak8 ^ (arow & 7);
    const int brbase = tid >> 3;      // B staging row base (+j*32)
    const int bk8    = tid & 7;

    // prefetch register buffer (double-buffers the LDS tile)
    float4 a0, a1;
    uint4  bh[4], bl[4];

    f32x4 accS[2][2], accT[2][2];
    #pragma unroll
    for (int m = 0; m < 2; ++m)
        #pragma unroll
        for (int n = 0; n < 2; ++n) {
            accS[m][n] = (f32x4){0.f, 0.f, 0.f, 0.f};
            accT[m][n] = (f32x4){0.f, 0.f, 0.f, 0.f};
        }

#define PREFETCH(fptr, Whi, Wlo, K, k0)                                          \
    {                                                                            \
        const float* fb = (fptr) + (size_t)(row0 + arow) * (K) + (k0) + ak8 * 8; \
        a0 = *(const float4*)fb;                                                 \
        a1 = *(const float4*)(fb + 4);                                           \
        _Pragma("unroll")                                                        \
        for (int j = 0; j < 4; ++j) {                                            \
            size_t off = (size_t)(brbase + j * 32) * (K) + (k0) + bk8 * 8;       \
            bh[j] = *(const uint4*)((Whi) + off);                                \
            bl[j] = *(const uint4*)((Wlo) + off);                                \
        }                                                                        \
    }

#define STAGE()                                                                  \
    {                                                                            \
        float av[8] = {a0.x, a0.y, a0.z, a0.w, a1.x, a1.y, a1.z, a1.w};          \
        u16x8 vh, vl;                                                            \
        _Pragma("unroll")                                                        \
        for (int i = 0; i < 8; ++i) {                                            \
            unsigned short h = f2bf(av[i]);                                      \
            vh[i] = h; vl[i] = f2bf(av[i] - bf2f(h));                            \
        }                                                                        \
        *(u16x8*)&sAhi[arow][achunk * 8] = vh;                                   \
        *(u16x8*)&sAlo[arow][achunk * 8] = vl;                                   \
        _Pragma("unroll")                                                        \
        for (int j = 0; j < 4; ++j) {                                            \
            int br = brbase + j * 32;                                            \
            int bc = (bk8 ^ (br & 7)) * 8;                                       \
            *(uint4*)&sBhi[br][bc] = bh[j];                                      \
            *(uint4*)&sBlo[br][bc] = bl[j];                                      \
        }                                                                        \
    }

#define MFMA_TILE(acc)                                                           \
    _Pragma("unroll")                                                            \
    for (int ks = 0; ks < 2; ++ks) {                                             \
        bf16x8 fah[2], fal[2], fbh[2], fbl[2];                                   \
        _Pragma("unroll")                                                        \
        for (int m = 0; m < 2; ++m) {                                            \
            int r = m * 16 + l15;                                                \
            int c = ((ks * 4 + l4) ^ (r & 7)) * 8;                               \
            fah[m] = *(const bf16x8*)&sAhi[r][c];                                \
            fal[m] = *(const bf16x8*)&sAlo[r][c];                                \
        }                                                                        \
        _Pragma("unroll")                                                        \
        for (int n = 0; n < 2; ++n) {                                            \
            int r = wn * 32 + n * 16 + l15;                                      \
            int c = ((ks * 4 + l4) ^ (r & 7)) * 8;                               \
            fbh[n] = *(const bf16x8*)&sBhi[r][c];                                \
            fbl[n] = *(const bf16x8*)&sBlo[r][c];                                \
        }                                                                        \
        _Pragma("unroll")                                                        \
        for (int m = 0; m < 2; ++m)                                              \
            _Pragma("unroll")                                                    \
            for (int n = 0; n < 2; ++n) {                                        \
                f32x4 cc = acc[m][n];                                            \
                cc = __builtin_amdgcn_mfma_f32_16x16x32_bf16(fah[m], fbh[n], cc, 0, 0, 0); \
                cc = __builtin_amdgcn_mfma_f32_16x16x32_bf16(fah[m], fbl[n], cc, 0, 0, 0); \
                cc = __builtin_amdgcn_mfma_f32_16x16x32_bf16(fal[m], fbh[n], cc, 0, 0, 0); \
                acc[m][n] = cc;                                                  \
            }                                                                    \
    }

    // ---- phase s: 12 tiles ----
    PREFETCH(f_s, WhiS, WloS, KS, 0);
    for (int kt = 0; kt < NTS; ++kt) {
        __syncthreads();               // prior tile fully consumed
        STAGE();
        __syncthreads();
        if (kt + 1 < NTS) { PREFETCH(f_s, WhiS, WloS, KS, (kt + 1) * KB); }
        else              { PREFETCH(f_t, WhiT, WloT, KT, 0); }
        MFMA_TILE(accS);               // hides the prefetch latency
    }
    // ---- phase t: 16 tiles ----
    for (int kt = 0; kt < NTT; ++kt) {
        __syncthreads();
        STAGE();
        __syncthreads();
        if (kt + 1 < NTT) { PREFETCH(f_t, WhiT, WloT, KT, (kt + 1) * KB); }
        MFMA_TILE(accT);
    }

    // ---- bias ----
    #pragma unroll
    for (int n = 0; n < 2; ++n) {
        int col = wn * 32 + n * 16 + l15;
        float bsv = b_s[col], btv = b_t[col];
        #pragma unroll
        for (int m = 0; m < 2; ++m) {
            accS[m][n] += bsv;
            accT[m][n] += btv;
        }
    }

    // ---- fused epilogue: per-row s2/t2/dot ----
    #pragma unroll
    for (int m = 0; m < 2; ++m) {
        #pragma unroll
        for (int r = 0; r < 4; ++r) {
            float s2 = accS[m][0][r] * accS[m][0][r] + accS[m][1][r] * accS[m][1][r];
            float t2 = accT[m][0][r] * accT[m][0][r] + accT[m][1][r] * accT[m][1][r];
            float dt = accS[m][0][r] * accT[m][0][r] + accS[m][1][r] * accT[m][1][r];
            #pragma unroll
            for (int d = 1; d < 16; d <<= 1) {
                s2 += __shfl_xor(s2, d, 64);
                t2 += __shfl_xor(t2, d, 64);
                dt += __shfl_xor(dt, d, 64);
            }
            if (l15 == 0) {
                int row = m * 16 + l4 * 4 + r;
                sRed[row][wn][0] = s2;
                sRed[row][wn][1] = t2;
                sRed[row][wn][2] = dt;
            }
        }
    }
    __syncthreads();
    if (tid < 32) {
        float s2 = sRed[tid][0][0] + sRed[tid][1][0] + sRed[tid][2][0] + sRed[tid][3][0];
        float t2 = sRed[tid][0][1] + sRed[tid][1][1] + sRed[tid][2][1] + sRed[tid][3][1];
        float dt = sRed[tid][0][2] + sRed[tid][1][2] + sRed[tid][2][2] + sRed[tid][3][2];
        float v = dt / sqrtf(s2 * t2);
        #pragma unroll
        for (int d = 1; d < 32; d <<= 1) v += __shfl_xor(v, d, 64);
        if (tid == 0) partials[blockIdx.x] = v;
    }
}

__global__ __launch_bounds__(256) void finalize(
    const float* __restrict__ partials, float* __restrict__ out)
{
    const int tid = threadIdx.x;
    float v = partials[tid] + partials[tid + 256];
    #pragma unroll
    for (int d = 1; d < 64; d <<= 1) v += __shfl_xor(v, d, 64);
    __shared__ float r[4];
    if ((tid & 63) == 0) r[tid >> 6] = v;
    __syncthreads();
    if (tid == 0) out[0] = -(r[0] + r[1] + r[2] + r[3]) / 16384.0f;
}

extern "C" void kernel_launch(void* const* d_in, const int* in_sizes, int n_in,
                              void* d_out, int out_size, void* d_ws, size_t ws_size,
                              hipStream_t stream)
{
    const float* f_s = (const float*)d_in[0];
    const float* f_t = (const float*)d_in[1];
    const float* W_s = (const float*)d_in[2];
    const float* b_s = (const float*)d_in[3];
    const float* W_t = (const float*)d_in[4];
    const float* b_t = (const float*)d_in[5];

    unsigned char* ws = (unsigned char*)d_ws;
    unsigned short* WhiS = (unsigned short*)(ws);
    unsigned short* WloS = (unsigned short*)(ws + 196608);
    unsigned short* WhiT = (unsigned short*)(ws + 393216);
    unsigned short* WloT = (unsigned short*)(ws + 655360);
    float*          part = (float*)(ws + 917504);

    convert_w<<<896, 256, 0, stream>>>(W_s, W_t, WhiS, WloS, WhiT, WloT);
    gemm_fused<<<512, 256, 0, stream>>>(f_s, f_t, WhiS, WloS, WhiT, WloT,
                                        b_s, b_t, part);
    finalize<<<1, 256, 0, stream>>>(part, (float*)d_out);
}

// Round 5
// 163.246 us; speedup vs baseline: 1.7570x; 1.7570x over previous
//
#include <hip/hip_runtime.h>
#include <math.h>

typedef __attribute__((ext_vector_type(8))) short bf16x8;
typedef __attribute__((ext_vector_type(8))) unsigned short u16x8;
typedef __attribute__((ext_vector_type(4))) float f32x4;

#define FEAT 128
#define KS   768
#define KT   1024
#define BM   32
#define KB   64

// LDS layout (80KB exactly -> 2 blocks/CU):
//   Bbuf b (b=0,1) at 32768*b : hi 16KB, lo 16KB (+16384)
//   Abuf b at 65536 + 8192*b  : hi 4KB,  lo 4KB  (+4096)
//   sRed aliases offset 0 (Bbuf0) -- epilogue only, after Bbuf0 is dead
#define BOFF(b) ((b) * 32768)
#define AOFF(b) (65536 + (b) * 8192)

__device__ __forceinline__ unsigned short f2bf(float f) {
    unsigned u = __float_as_uint(f);
    u += 0x7fff + ((u >> 16) & 1);   // RNE; inputs well-scaled, no NaN/Inf
    return (unsigned short)(u >> 16);
}
__device__ __forceinline__ float bf2f(unsigned short h) {
    return __uint_as_float((unsigned)h << 16);
}

// Split W_s, W_t into bf16 hi/lo (same flat [FEAT][K] layout as source).
__global__ __launch_bounds__(256) void convert_w(
    const float* __restrict__ Ws, const float* __restrict__ Wt,
    unsigned short* __restrict__ WhiS, unsigned short* __restrict__ WloS,
    unsigned short* __restrict__ WhiT, unsigned short* __restrict__ WloT)
{
    const int NS = FEAT * KS;
    int e = blockIdx.x * 256 + threadIdx.x;
    if (e < NS) {
        float w = Ws[e];
        unsigned short h = f2bf(w);
        WhiS[e] = h;
        WloS[e] = f2bf(w - bf2f(h));
    } else {
        int e2 = e - NS;
        float w = Wt[e2];
        unsigned short h = f2bf(w);
        WhiT[e2] = h;
        WloT[e2] = f2bf(w - bf2f(h));
    }
}

// BM=32 rows/block, BOTH embeddings, bf16x3 MFMA, fused norm/dot epilogue.
// 256 threads = 4 waves (1M x 4N); per wave 32x32 out = 2x2 16x16 frags.
// B: global_load_lds width=16 (zero VGPR staging), source pre-swizzled
//    (seg ^= row&7) so the swizzled READ is conflict-free (rule #21).
// A: reg-staged fp32->bf16 hi/lo, ping-pong reg sets (nothing live across MFMA).
__global__ __launch_bounds__(256, 2) void gemm_fused(
    const float* __restrict__ f_s, const float* __restrict__ f_t,
    const unsigned short* __restrict__ WhiS, const unsigned short* __restrict__ WloS,
    const unsigned short* __restrict__ WhiT, const unsigned short* __restrict__ WloT,
    const float* __restrict__ b_s, const float* __restrict__ b_t,
    float* __restrict__ partials)
{
    __shared__ __align__(16) unsigned char smem[81920];

    const int tid  = threadIdx.x;
    const int lane = tid & 63;
    const int wn   = tid >> 6;        // 0..3 (N split of FEAT)
    const int l15  = lane & 15;
    const int l4   = lane >> 4;
    const int row0 = blockIdx.x * BM;

    const int arow  = tid >> 3;       // 0..31 A staging row
    const int ak8   = tid & 7;        // 8-elem k-seg
    const int aslot = ak8 ^ (arow & 7);

    float4 aA0, aA1, aB0, aB1;        // two A-prefetch reg sets (ping-pong)

    f32x4 accS[2][2], accT[2][2];
    #pragma unroll
    for (int m = 0; m < 2; ++m)
        #pragma unroll
        for (int n = 0; n < 2; ++n) {
            accS[m][n] = (f32x4){0.f, 0.f, 0.f, 0.f};
            accT[m][n] = (f32x4){0.f, 0.f, 0.f, 0.f};
        }

// Issue 8 async global->LDS loads for one B tile (hi+lo), linear LDS dest,
// XOR-pre-swizzled global source.
#define GLL_B(Whi, Wlo, K, k0, boff)                                               \
    { _Pragma("unroll")                                                            \
      for (int j = 0; j < 4; ++j) {                                                \
        int chunk = j * 256 + tid;                                                 \
        int brow  = chunk >> 3;                                                    \
        int bseg  = (chunk & 7) ^ (brow & 7);                                      \
        size_t goff = (size_t)brow * (K) + (k0) + bseg * 8;                        \
        __builtin_amdgcn_global_load_lds(                                          \
            (const __attribute__((address_space(1))) unsigned int*)((Whi) + goff), \
            (__attribute__((address_space(3))) unsigned int*)(smem + (boff) + chunk * 16), \
            16, 0, 0);                                                             \
        __builtin_amdgcn_global_load_lds(                                          \
            (const __attribute__((address_space(1))) unsigned int*)((Wlo) + goff), \
            (__attribute__((address_space(3))) unsigned int*)(smem + (boff) + 16384 + chunk * 16), \
            16, 0, 0);                                                             \
      } }

#define LOAD_A(r0v, r1v, f, K, k0)                                             \
    { const float* fb = (f) + (size_t)(row0 + arow) * (K) + (k0) + ak8 * 8;    \
      r0v = *(const float4*)fb;  r1v = *(const float4*)(fb + 4); }

#define STAGE_A(aoff, r0v, r1v)                                                \
    { float av[8] = {r0v.x, r0v.y, r0v.z, r0v.w, r1v.x, r1v.y, r1v.z, r1v.w};  \
      u16x8 vh, vl;                                                            \
      _Pragma("unroll")                                                        \
      for (int i = 0; i < 8; ++i) {                                            \
          unsigned short h = f2bf(av[i]);                                      \
          vh[i] = h; vl[i] = f2bf(av[i] - bf2f(h));                            \
      }                                                                        \
      *(u16x8*)(smem + (aoff) + arow * 128 + aslot * 16) = vh;                 \
      *(u16x8*)(smem + (aoff) + 4096 + arow * 128 + aslot * 16) = vl; }

#define MFMA_T(aoff, boff, acc)                                                \
    _Pragma("unroll")                                                          \
    for (int ks = 0; ks < 2; ++ks) {                                           \
        bf16x8 fah[2], fal[2], fbh[2], fbl[2];                                 \
        _Pragma("unroll")                                                      \
        for (int m = 0; m < 2; ++m) {                                          \
            int r  = m * 16 + l15;                                             \
            int cs = (ks * 4 + l4) ^ (r & 7);                                  \
            fah[m] = *(const bf16x8*)(smem + (aoff) + r * 128 + cs * 16);      \
            fal[m] = *(const bf16x8*)(smem + (aoff) + 4096 + r * 128 + cs * 16); \
        }                                                                      \
        _Pragma("unroll")                                                      \
        for (int n = 0; n < 2; ++n) {                                          \
            int r  = wn * 32 + n * 16 + l15;                                   \
            int cs = (ks * 4 + l4) ^ (r & 7);                                  \
            fbh[n] = *(const bf16x8*)(smem + (boff) + r * 128 + cs * 16);      \
            fbl[n] = *(const bf16x8*)(smem + (boff) + 16384 + r * 128 + cs * 16); \
        }                                                                      \
        _Pragma("unroll")                                                      \
        for (int m = 0; m < 2; ++m)                                            \
            _Pragma("unroll")                                                  \
            for (int n = 0; n < 2; ++n) {                                      \
                f32x4 cc = acc[m][n];                                          \
                cc = __builtin_amdgcn_mfma_f32_16x16x32_bf16(fah[m], fbh[n], cc, 0, 0, 0); \
                cc = __builtin_amdgcn_mfma_f32_16x16x32_bf16(fah[m], fbl[n], cc, 0, 0, 0); \
                cc = __builtin_amdgcn_mfma_f32_16x16x32_bf16(fal[m], fbh[n], cc, 0, 0, 0); \
                acc[m][n] = cc;                                                \
            }                                                                  \
    }

    // ---------- prologue: s tile 0 resident, aA = A(s1) ----------
    GLL_B(WhiS, WloS, KS, 0, BOFF(0));
    LOAD_A(aB0, aB1, f_s, KS, 0);
    STAGE_A(AOFF(0), aB0, aB1);
    LOAD_A(aA0, aA1, f_s, KS, KB);
    __syncthreads();

    // ---------- s-phase: tile pairs (0,1)..(8,9) ----------
    for (int p = 0; p < 5; ++p) {
        const int t0 = 2 * p;
        GLL_B(WhiS, WloS, KS, (t0 + 1) * KB, BOFF(1));
        LOAD_A(aB0, aB1, f_s, KS, (t0 + 2) * KB);
        MFMA_T(AOFF(0), BOFF(0), accS);          // tile t0
        STAGE_A(AOFF(1), aA0, aA1);              // tile t0+1
        __syncthreads();
        GLL_B(WhiS, WloS, KS, (t0 + 2) * KB, BOFF(0));
        LOAD_A(aA0, aA1, f_s, KS, (t0 + 3) * KB);
        MFMA_T(AOFF(1), BOFF(1), accS);          // tile t0+1
        STAGE_A(AOFF(0), aB0, aB1);              // tile t0+2
        __syncthreads();
    }

    // ---------- transition: s tiles 10,11 ; prefetch t tiles 0,1 ----------
    GLL_B(WhiS, WloS, KS, 11 * KB, BOFF(1));
    LOAD_A(aB0, aB1, f_t, KT, 0);
    MFMA_T(AOFF(0), BOFF(0), accS);              // s10
    STAGE_A(AOFF(1), aA0, aA1);                  // s11
    __syncthreads();
    GLL_B(WhiT, WloT, KT, 0, BOFF(0));
    LOAD_A(aA0, aA1, f_t, KT, KB);
    MFMA_T(AOFF(1), BOFF(1), accS);              // s11
    STAGE_A(AOFF(0), aB0, aB1);                  // t0
    __syncthreads();

    // ---------- t-phase: tile pairs (0,1)..(12,13) ----------
    for (int p = 0; p < 7; ++p) {
        const int t0 = 2 * p;
        GLL_B(WhiT, WloT, KT, (t0 + 1) * KB, BOFF(1));
        LOAD_A(aB0, aB1, f_t, KT, (t0 + 2) * KB);
        MFMA_T(AOFF(0), BOFF(0), accT);          // tile t0
        STAGE_A(AOFF(1), aA0, aA1);              // tile t0+1
        __syncthreads();
        GLL_B(WhiT, WloT, KT, (t0 + 2) * KB, BOFF(0));
        LOAD_A(aA0, aA1, f_t, KT, (t0 + 3) * KB);
        MFMA_T(AOFF(1), BOFF(1), accT);          // tile t0+1
        STAGE_A(AOFF(0), aB0, aB1);              // tile t0+2
        __syncthreads();
    }

    // ---------- final: t tiles 14,15 ----------
    GLL_B(WhiT, WloT, KT, 15 * KB, BOFF(1));
    MFMA_T(AOFF(0), BOFF(0), accT);              // t14
    STAGE_A(AOFF(1), aA0, aA1);                  // t15
    __syncthreads();
    MFMA_T(AOFF(1), BOFF(1), accT);              // t15 (reads bufs 1 only)

    // ---- bias ----
    #pragma unroll
    for (int n = 0; n < 2; ++n) {
        int col = wn * 32 + n * 16 + l15;
        float bsv = b_s[col], btv = b_t[col];
        #pragma unroll
        for (int m = 0; m < 2; ++m) {
            accS[m][n] += bsv;
            accT[m][n] += btv;
        }
    }

    // ---- fused epilogue: per-row s2/t2/dot (sRed aliases dead Bbuf0) ----
    float (*sRed)[4][3] = (float (*)[4][3])smem;
    #pragma unroll
    for (int m = 0; m < 2; ++m) {
        #pragma unroll
        for (int r = 0; r < 4; ++r) {
            float s2 = accS[m][0][r] * accS[m][0][r] + accS[m][1][r] * accS[m][1][r];
            float t2 = accT[m][0][r] * accT[m][0][r] + accT[m][1][r] * accT[m][1][r];
            float dt = accS[m][0][r] * accT[m][0][r] + accS[m][1][r] * accT[m][1][r];
            #pragma unroll
            for (int d = 1; d < 16; d <<= 1) {
                s2 += __shfl_xor(s2, d, 64);
                t2 += __shfl_xor(t2, d, 64);
                dt += __shfl_xor(dt, d, 64);
            }
            if (l15 == 0) {
                int row = m * 16 + l4 * 4 + r;
                sRed[row][wn][0] = s2;
                sRed[row][wn][1] = t2;
                sRed[row][wn][2] = dt;
            }
        }
    }
    __syncthreads();
    if (tid < 32) {
        float s2 = sRed[tid][0][0] + sRed[tid][1][0] + sRed[tid][2][0] + sRed[tid][3][0];
        float t2 = sRed[tid][0][1] + sRed[tid][1][1] + sRed[tid][2][1] + sRed[tid][3][1];
        float dt = sRed[tid][0][2] + sRed[tid][1][2] + sRed[tid][2][2] + sRed[tid][3][2];
        float v = dt / sqrtf(s2 * t2);
        #pragma unroll
        for (int d = 1; d < 32; d <<= 1) v += __shfl_xor(v, d, 64);
        if (tid == 0) partials[blockIdx.x] = v;
    }
}

__global__ __launch_bounds__(256) void finalize(
    const float* __restrict__ partials, float* __restrict__ out)
{
    const int tid = threadIdx.x;
    float v = partials[tid] + partials[tid + 256];
    #pragma unroll
    for (int d = 1; d < 64; d <<= 1) v += __shfl_xor(v, d, 64);
    __shared__ float r[4];
    if ((tid & 63) == 0) r[tid >> 6] = v;
    __syncthreads();
    if (tid == 0) out[0] = -(r[0] + r[1] + r[2] + r[3]) / 16384.0f;
}

extern "C" void kernel_launch(void* const* d_in, const int* in_sizes, int n_in,
                              void* d_out, int out_size, void* d_ws, size_t ws_size,
                              hipStream_t stream)
{
    const float* f_s = (const float*)d_in[0];
    const float* f_t = (const float*)d_in[1];
    const float* W_s = (const float*)d_in[2];
    const float* b_s = (const float*)d_in[3];
    const float* W_t = (const float*)d_in[4];
    const float* b_t = (const float*)d_in[5];

    unsigned char* ws = (unsigned char*)d_ws;
    unsigned short* WhiS = (unsigned short*)(ws);
    unsigned short* WloS = (unsigned short*)(ws + 196608);
    unsigned short* WhiT = (unsigned short*)(ws + 393216);
    unsigned short* WloT = (unsigned short*)(ws + 655360);
    float*          part = (float*)(ws + 917504);

    convert_w<<<896, 256, 0, stream>>>(W_s, W_t, WhiS, WloS, WhiT, WloT);
    gemm_fused<<<512, 256, 0, stream>>>(f_s, f_t, WhiS, WloS, WhiT, WloT,
                                        b_s, b_t, part);
    finalize<<<1, 256, 0, stream>>>(part, (float*)d_out);
}